// Round 9
// baseline (420.330 us; speedup 1.0000x reference)
//
#include <hip/hip_runtime.h>
#include <hip/hip_bf16.h>

#define B_ 4096
#define K_ 64
#define N_ 100000
#define E_ 128
#define T_ 3

typedef __bf16 bf16x8 __attribute__((ext_vector_type(8)));
typedef float  f32x4  __attribute__((ext_vector_type(4)));

static __device__ __forceinline__ bf16x8 cvt8r(f32x4 u, f32x4 v) {
    bf16x8 o;
    o[0] = (__bf16)u[0]; o[1] = (__bf16)u[1]; o[2] = (__bf16)u[2]; o[3] = (__bf16)u[3];
    o[4] = (__bf16)v[0]; o[5] = (__bf16)v[1]; o[6] = (__bf16)v[2]; o[7] = (__bf16)v[3];
    return o;
}

typedef const __attribute__((address_space(1))) void GAS;
typedef __attribute__((address_space(3))) void LAS;
static __device__ __forceinline__ void gload16(const void* g, void* l) {
    __builtin_amdgcn_global_load_lds((GAS*)g, (LAS*)l, 16, 0, 0);
}

#define MFMA16(a, b, c) __builtin_amdgcn_mfma_f32_16x16x32_bf16((a), (b), (c), 0, 0, 0)

// ---------------------------------------------------------------------------
// Kernel 0: transpose + bf16-convert weight matrices.
// ---------------------------------------------------------------------------
__global__ __launch_bounds__(256)
void k_prep(const float* __restrict__ W_f, const float* __restrict__ Wa1,
            const float* __restrict__ Wa2, const float* __restrict__ W1,
            __bf16* __restrict__ WtF, __bf16* __restrict__ Wa1t,
            __bf16* __restrict__ Wa2t, __bf16* __restrict__ W1t) {
    const int n = blockIdx.x;
    const int k = threadIdx.x;
    if (blockIdx.y == 0) {
        WtF[n * 256 + k] = (__bf16)W_f[k * 128 + n];
    } else if (blockIdx.y == 1) {
        if (k < 128) Wa1t[n * 128 + k] = (__bf16)Wa1[k * 128 + n];
    } else if (blockIdx.y == 2) {
        if (k < 128) Wa2t[n * 128 + k] = (__bf16)Wa2[k * 128 + n];
    } else {
        if (k < 128) W1t[n * 128 + k] = (__bf16)W1[k * 128 + n];
    }
}

// ---------------------------------------------------------------------------
// Kernel 1: nodes_fusion
// ---------------------------------------------------------------------------
__global__ __launch_bounds__(128)
void k_node_fusion(const int* __restrict__ nodes,
                   const float* __restrict__ node_emb,
                   const float* __restrict__ node_prof,
                   const float* __restrict__ W_f, const float* __restrict__ b_f,
                   __bf16* __restrict__ nodes_fusion) {
    __shared__ float x[256];
    const int b = blockIdx.x;
    const int e = threadIdx.x;
    const int nd = nodes[b];
    x[e]       = node_emb[(size_t)nd * E_ + e];
    x[128 + e] = node_prof[(size_t)nd * E_ + e];
    __syncthreads();
    float acc = b_f[e];
#pragma unroll 8
    for (int i = 0; i < 256; ++i) acc = fmaf(x[i], W_f[i * E_ + e], acc);
    nodes_fusion[(size_t)b * E_ + e] = (__bf16)fmaxf(acc, 0.f);
}

// ---------------------------------------------------------------------------
// Kernel 1b: node_pre (f32)
// ---------------------------------------------------------------------------
__global__ __launch_bounds__(128)
void k_node_pre(const __bf16* __restrict__ nodes_fusion,
                const float* __restrict__ Wa1, const float* __restrict__ ba1,
                float* __restrict__ node_pre) {
    __shared__ float x[128];
    const int b = blockIdx.x;
    const int c = threadIdx.x;
    x[c] = (float)nodes_fusion[(size_t)b * E_ + c];
    __syncthreads();
    float acc = ba1[c];
#pragma unroll 8
    for (int i = 0; i < 128; ++i) acc = fmaf(x[i], Wa1[(128 + i) * E_ + c], acc);
    node_pre[(size_t)b * E_ + c] = acc;
}

// ---------------------------------------------------------------------------
// Kernel NF v4 (unchanged from round 8): persistent pipelined precompute.
// ---------------------------------------------------------------------------
#define NF_GRID 1024
#define NF_TPT (N_ / 16)
#define NF_NJOB (NF_TPT * T_)

__global__ __launch_bounds__(256, 4)
void k_nf(const float* __restrict__ neigh_emb,
          const float* __restrict__ neigh_prof,
          const __bf16* __restrict__ WtF, const float* __restrict__ b_f,
          __bf16* __restrict__ NFt) {
    __shared__ __align__(16) float  Xf[2][16 * 256];
    __shared__ __align__(16) __bf16 NFl[16 * 128];

    const int tid  = threadIdx.x;
    const int wid  = tid >> 6, lane = tid & 63;
    const int lr   = lane & 15, lk = lane >> 4;

    bf16x8 wf[16];
#pragma unroll
    for (int ks = 0; ks < 8; ++ks)
#pragma unroll
        for (int n = 0; n < 2; ++n)
            wf[ks * 2 + n] = *(const bf16x8*)&WtF[
                (size_t)(wid * 32 + n * 16 + lr) * 256 + ks * 32 + lk * 8];
    const float bb0 = b_f[wid * 32 + lr];
    const float bb1 = b_f[wid * 32 + 16 + lr];

    auto stage = [&](int j, int buf) {
        const int t    = j / NF_TPT;
        const int base = (j - t * NF_TPT) * 16;
        const float* embT  = neigh_emb  + (size_t)t * N_ * E_;
        const float* profT = neigh_prof + (size_t)t * N_ * E_;
#pragma unroll
        for (int i = 0; i < 4; ++i) {
            const int r  = wid * 4 + i;
            const int id = base + r;
            const int g  = lane ^ (r & 15);
            const float* src = (g < 32)
                ? embT  + (size_t)id * E_ + g * 4
                : profT + (size_t)id * E_ + (g - 32) * 4;
            gload16(src, (char*)&Xf[buf][0] + r * 1024);
        }
    };

    int job = blockIdx.x;
    stage(job, 0);
    int cur = 0;
    bool first = true;

    for (; job < NF_NJOB; job += NF_GRID) {
        const int tc    = job / NF_TPT;
        const int basec = (job - tc * NF_TPT) * 16;

        if (first) { asm volatile("s_waitcnt vmcnt(0)" ::: "memory"); first = false; }
        else       { asm volatile("s_waitcnt vmcnt(1)" ::: "memory"); }
        __builtin_amdgcn_s_barrier();
        __builtin_amdgcn_sched_barrier(0);

        const int nxt = job + NF_GRID;
        if (nxt < NF_NJOB) stage(nxt, cur ^ 1);

        const float* X = &Xf[cur][0];

        {
            f32x4 acc1[2] = {};
#pragma unroll
            for (int ks = 0; ks < 8; ++ks) {
                const int g0 = ks * 8 + lk * 2;
                const f32x4 u0 = *(const f32x4*)&X[lr * 256 + ((g0 ^ lr) << 2)];
                const f32x4 v0 = *(const f32x4*)&X[lr * 256 + (((g0 + 1) ^ lr) << 2)];
                const bf16x8 a0 = cvt8r(u0, v0);
                acc1[0] = MFMA16(a0, wf[ks * 2 + 0], acc1[0]);
                acc1[1] = MFMA16(a0, wf[ks * 2 + 1], acc1[1]);
            }
#pragma unroll
            for (int n = 0; n < 2; ++n) {
                const int c = wid * 32 + n * 16 + lr;
                const float bb = n ? bb1 : bb0;
                const int q = c >> 3, eo = c & 7;
#pragma unroll
                for (int j = 0; j < 4; ++j) {
                    const int rN = lk * 4 + j;
                    NFl[rN * 128 + ((q ^ rN) << 3) + eo] =
                        (__bf16)fmaxf(acc1[n][j] + bb, 0.f);
                }
            }
        }
        asm volatile("s_waitcnt lgkmcnt(0)" ::: "memory");
        __builtin_amdgcn_s_barrier();
        __builtin_amdgcn_sched_barrier(0);

        {
            const int rr = tid >> 4, qq = tid & 15;
            const int p = qq ^ (rr & 15);
            __bf16* outp = NFt + ((size_t)tc * N_ + basec + rr) * E_ + qq * 8;
            *(bf16x8*)outp = *(const bf16x8*)&NFl[rr * 128 + (p << 3)];
        }
        cur ^= 1;
    }
}

// ---------------------------------------------------------------------------
// Kernel ATT v3: persistent pipelined. 768 blocks (3/CU), grid-stride over
// 12288 (t,b) jobs (job = t*B + b). Double-buffered Nb gather; weights in
// VGPRs (compute phase has zero vmem). 4 uniform barriers / job.
// Per wave: cols wid*32..+32 in GEMM2 & GEMM3 over all 64 rows.
// ---------------------------------------------------------------------------
#define ATT_GRID 768
#define ATT_NJOB (B_ * T_)
#define ATT_NITER (ATT_NJOB / ATT_GRID)   /* 16, exact */

__global__ __launch_bounds__(256, 3)
void k_att(const int* __restrict__ neigh_idx,
           const __bf16* __restrict__ NFt,
           const __bf16* __restrict__ Wa1t,
           const __bf16* __restrict__ Wa2t,
           const float* __restrict__ ba2,
           const float* __restrict__ Wa3, const float* __restrict__ ba3,
           const float* __restrict__ node_pre,
           __bf16* __restrict__ aggB) {
    __shared__ __align__(16) __bf16 Nb[2][64 * 128];   // 2 x 16 KB
    __shared__ __align__(16) __bf16 H1l[64 * 128];     // 16 KB
    __shared__ float scp[4 * 64];                      // 1 KB
    __shared__ float red4[4 * 128];                    // 2 KB

    const int tid = threadIdx.x;
    const int wid = tid >> 6, lane = tid & 63;
    const int lr = lane & 15, lk = lane >> 4;

    // ---- preload weights (wave owns cols wid*32..+32 in BOTH GEMMs) ----
    bf16x8 wa1r[8], wa2r[8];
#pragma unroll
    for (int ks = 0; ks < 4; ++ks)
#pragma unroll
        for (int n = 0; n < 2; ++n) {
            wa1r[ks * 2 + n] = *(const bf16x8*)&Wa1t[
                (size_t)(wid * 32 + n * 16 + lr) * 128 + ks * 32 + lk * 8];
            wa2r[ks * 2 + n] = *(const bf16x8*)&Wa2t[
                (size_t)(wid * 32 + n * 16 + lr) * 128 + ks * 32 + lk * 8];
        }
    float ba2r[2], wa3r[2];
#pragma unroll
    for (int n = 0; n < 2; ++n) {
        ba2r[n] = ba2[wid * 32 + n * 16 + lr];
        wa3r[n] = Wa3[wid * 32 + n * 16 + lr];
    }
    const float ba3v = ba3[0];

    // DMA stage: per-lane ids in idv (lane m<16 holds row wid*16+m)
    auto stage = [&](int j, int buf, int idv) {
        const int t = j / B_;
        const __bf16* tab = NFt + (size_t)t * N_ * E_;
#pragma unroll
        for (int i = 0; i < 4; ++i) {
            const int rowblock = wid * 16 + i * 4;
            const int rsub = i * 4 + (lane >> 4);        // == row & 15
            const int q = (lane & 15) ^ rsub;
            const int id = __shfl(idv, rsub);
            gload16(tab + (size_t)id * E_ + q * 8,
                    (char*)&Nb[buf][0] + rowblock * 256);
        }
    };

    int job = blockIdx.x;
    // prologue: stage job, prefetch npre(job) + idx(job+G) + npre... invariant:
    //   loop-top: npn = npre(job), idnext = idx(job+GRID)
    {
        const int idv0 = neigh_idx[(size_t)job * K_ + wid * 16 + (lane & 15)];
        stage(job, 0, idv0);
    }
    float npn0 = node_pre[(size_t)(job % B_) * E_ + wid * 32 + lr];
    float npn1 = node_pre[(size_t)(job % B_) * E_ + wid * 32 + 16 + lr];
    int jn = job + ATT_GRID; if (jn >= ATT_NJOB) jn = ATT_NJOB - 1;
    int idnext = neigh_idx[(size_t)jn * K_ + wid * 16 + (lane & 15)];
    int cur = 0;

    for (int it = 0; it < ATT_NITER; ++it, job += ATT_GRID) {
        asm volatile("s_waitcnt vmcnt(0)" ::: "memory");
        __builtin_amdgcn_s_barrier();
        __builtin_amdgcn_sched_barrier(0);

        const float np0 = npn0, np1 = npn1;   // npre for CURRENT job

        if (it + 1 < ATT_NITER) {
            stage(job + ATT_GRID, cur ^ 1, idnext);
            int j2 = job + 2 * ATT_GRID; if (j2 >= ATT_NJOB) j2 = ATT_NJOB - 1;
            idnext = neigh_idx[(size_t)j2 * K_ + wid * 16 + (lane & 15)];
            const int bn = (job + ATT_GRID) % B_;
            npn0 = node_pre[(size_t)bn * E_ + wid * 32 + lr];
            npn1 = node_pre[(size_t)bn * E_ + wid * 32 + 16 + lr];
        }

        const __bf16* NbC = &Nb[cur][0];

        // ---- GEMM2: H1 = relu(NF @ Wa1t + npre), K=128 ----
        {
            f32x4 acc2[4][2] = {};
#pragma unroll
            for (int ks = 0; ks < 4; ++ks) {
                const int q = ks * 4 + lk;
                bf16x8 a[4];
#pragma unroll
                for (int mi = 0; mi < 4; ++mi)
                    a[mi] = *(const bf16x8*)&NbC[(mi * 16 + lr) * 128 + ((q ^ lr) << 3)];
#pragma unroll
                for (int n = 0; n < 2; ++n)
#pragma unroll
                    for (int mi = 0; mi < 4; ++mi)
                        acc2[mi][n] = MFMA16(a[mi], wa1r[ks * 2 + n], acc2[mi][n]);
            }
#pragma unroll
            for (int n = 0; n < 2; ++n) {
                const int col = wid * 32 + n * 16 + lr;
                const float pp = n ? np1 : np0;
                const int q = col >> 3, eo = col & 7;
#pragma unroll
                for (int mi = 0; mi < 4; ++mi)
#pragma unroll
                    for (int j = 0; j < 4; ++j) {
                        const int row = mi * 16 + lk * 4 + j;
                        H1l[row * 128 + ((q ^ (row & 15)) << 3) + eo] =
                            (__bf16)fmaxf(acc2[mi][n][j] + pp, 0.f);
                    }
            }
        }
        asm volatile("s_waitcnt lgkmcnt(0)" ::: "memory");
        __builtin_amdgcn_s_barrier();
        __builtin_amdgcn_sched_barrier(0);

        // ---- GEMM3: H2 = relu(H1 @ Wa2 + ba2) -> score partials ----
        {
            f32x4 acc3[4][2] = {};
#pragma unroll
            for (int ks = 0; ks < 4; ++ks) {
                const int q = ks * 4 + lk;
                bf16x8 a[4];
#pragma unroll
                for (int mi = 0; mi < 4; ++mi)
                    a[mi] = *(const bf16x8*)&H1l[(mi * 16 + lr) * 128 + ((q ^ lr) << 3)];
#pragma unroll
                for (int n = 0; n < 2; ++n)
#pragma unroll
                    for (int mi = 0; mi < 4; ++mi)
                        acc3[mi][n] = MFMA16(a[mi], wa2r[ks * 2 + n], acc3[mi][n]);
            }
#pragma unroll
            for (int mi = 0; mi < 4; ++mi)
#pragma unroll
                for (int j = 0; j < 4; ++j) {
                    float v = fmaxf(acc3[mi][0][j] + ba2r[0], 0.f) * wa3r[0]
                            + fmaxf(acc3[mi][1][j] + ba2r[1], 0.f) * wa3r[1];
                    v += __shfl_xor(v, 1);
                    v += __shfl_xor(v, 2);
                    v += __shfl_xor(v, 4);
                    v += __shfl_xor(v, 8);
                    if (lr == 0)
                        scp[wid * 64 + mi * 16 + lk * 4 + j] = v;
                }
        }
        asm volatile("s_waitcnt lgkmcnt(0)" ::: "memory");
        __builtin_amdgcn_s_barrier();
        __builtin_amdgcn_sched_barrier(0);

        // ---- softmax over K=64, redundantly in every wave (att in regs) ----
        float att;
        {
            const float v = scp[lane] + scp[64 + lane] + scp[128 + lane]
                          + scp[192 + lane] + ba3v;
            float m = v;
#pragma unroll
            for (int o = 32; o > 0; o >>= 1) m = fmaxf(m, __shfl_xor(m, o));
            const float pe = __expf(v - m);
            float s = pe;
#pragma unroll
            for (int o = 32; o > 0; o >>= 1) s += __shfl_xor(s, o);
            att = pe / s;                       // lane holds att[neighbor=lane]
        }

        // ---- agg partials: wave wid covers rows wid*16..+15, lane -> e,e+64 ----
        {
            float p0 = 0.f, p1 = 0.f;
            const int q0 = lane >> 3, eo = lane & 7;
            const int q1 = (lane + 64) >> 3;
#pragma unroll
            for (int i = 0; i < 16; ++i) {
                const int row = wid * 16 + i;
                const float av = __shfl(att, row);
                p0 = fmaf(av, (float)NbC[row * 128 + ((q0 ^ (row & 15)) << 3) + eo], p0);
                p1 = fmaf(av, (float)NbC[row * 128 + ((q1 ^ (row & 15)) << 3) + eo], p1);
            }
            red4[wid * 128 + lane] = p0;
            red4[wid * 128 + 64 + lane] = p1;
        }
        asm volatile("s_waitcnt lgkmcnt(0)" ::: "memory");
        __builtin_amdgcn_s_barrier();
        __builtin_amdgcn_sched_barrier(0);

        if (tid < 128) {
            const float s = red4[tid] + red4[128 + tid] + red4[256 + tid]
                          + red4[384 + tid];
            const int bcur = job % B_, tcur = job / B_;
            aggB[((size_t)bcur * T_ + tcur) * E_ + tid] = (__bf16)s;
        }
        cur ^= 1;
    }
}

// ---------------------------------------------------------------------------
// Kernel 2b: type_agg = relu(aggB @ W1 + b1), M=B*T=12288, K=N=128.
// ---------------------------------------------------------------------------
__global__ __launch_bounds__(256)
void k_w1(const __bf16* __restrict__ aggB, const __bf16* __restrict__ W1t,
          const float* __restrict__ b1, __bf16* __restrict__ type_agg) {
    const int tid  = threadIdx.x;
    const int wid  = tid >> 6;
    const int lane = tid & 63;
    const int lr   = lane & 15;
    const int lk   = lane >> 4;
    const int rbase = blockIdx.x * 64 + wid * 16;

    f32x4 acc[8] = {};
#pragma unroll
    for (int ks = 0; ks < 4; ++ks) {
        const bf16x8 a = *(const bf16x8*)&aggB[(size_t)(rbase + lr) * 128 + ks * 32 + lk * 8];
        const __bf16* wb = W1t + (size_t)lr * 128 + ks * 32 + lk * 8;
#pragma unroll
        for (int n = 0; n < 8; ++n) {
            const bf16x8 w = *(const bf16x8*)(wb + (size_t)n * 16 * 128);
            acc[n] = MFMA16(a, w, acc[n]);
        }
    }
#pragma unroll
    for (int n = 0; n < 8; ++n) {
        const int col = n * 16 + lr;
        const float bb = b1[col];
#pragma unroll
        for (int j = 0; j < 4; ++j) {
            const int row = rbase + lk * 4 + j;
            type_agg[(size_t)row * 128 + col] = (__bf16)fmaxf(acc[n][j] + bb, 0.f);
        }
    }
}

// ---------------------------------------------------------------------------
// Kernel 3: type softmax + final MLP + output head.
// ---------------------------------------------------------------------------
__global__ __launch_bounds__(128)
void k_final(const __bf16* __restrict__ type_agg,
             const __bf16* __restrict__ nodes_fusion,
             const float* __restrict__ Wt,
             const float* __restrict__ W2, const float* __restrict__ b2,
             const float* __restrict__ Wc, const float* __restrict__ bc,
             float* __restrict__ out, float* __restrict__ att_out) {
    __shared__ float ta[384];
    __shared__ float nfu[128];
    __shared__ float fin[128];
    __shared__ float hb[128];
    __shared__ float att[3];
    __shared__ float red[3][128];

    const int b = blockIdx.x;
    const int e = threadIdx.x;

    const float v0 = (float)type_agg[(size_t)b * 384 + e];
    const float v1 = (float)type_agg[(size_t)b * 384 + 128 + e];
    const float v2 = (float)type_agg[(size_t)b * 384 + 256 + e];
    ta[e] = v0; ta[128 + e] = v1; ta[256 + e] = v2;
    nfu[e] = (float)nodes_fusion[(size_t)b * E_ + e];

    float p0, p1, p2;
    {
        const float* w0 = Wt + (size_t)e * 3;
        const float* w1 = Wt + (size_t)(128 + e) * 3;
        const float* w2 = Wt + (size_t)(256 + e) * 3;
        p0 = v0 * w0[0] + v1 * w1[0] + v2 * w2[0];
        p1 = v0 * w0[1] + v1 * w1[1] + v2 * w2[1];
        p2 = v0 * w0[2] + v1 * w1[2] + v2 * w2[2];
    }
    red[0][e] = p0; red[1][e] = p1; red[2][e] = p2;
    __syncthreads();

    if (e < 3) {
        float s = 0.f;
        for (int i = 0; i < 128; ++i) s += red[e][i];
        red[e][0] = s;
    }
    __syncthreads();
    if (e == 0) {
        const float s0 = red[0][0], s1 = red[1][0], s2 = red[2][0];
        const float m  = fmaxf(s0, fmaxf(s1, s2));
        const float e0 = __expf(s0 - m), e1 = __expf(s1 - m), e2 = __expf(s2 - m);
        const float inv = 1.f / (e0 + e1 + e2);
        att[0] = e0 * inv; att[1] = e1 * inv; att[2] = e2 * inv;
    }
    __syncthreads();

    fin[e] = att[0] * ta[e] + att[1] * ta[128 + e] + att[2] * ta[256 + e];
    __syncthreads();

    float acc = b2[e];
#pragma unroll 8
    for (int i = 0; i < 128; ++i) acc = fmaf(fin[i], W2[i * E_ + e], acc);
    hb[e] = fmaxf(acc, 0.f);
    __syncthreads();

    float acc2 = bc[e];
#pragma unroll 8
    for (int i = 0; i < 128; ++i) acc2 = fmaf(nfu[i], Wc[i * E_ + e], acc2);
#pragma unroll 8
    for (int i = 0; i < 128; ++i) acc2 = fmaf(hb[i], Wc[(128 + i) * E_ + e], acc2);
    out[(size_t)b * E_ + e] = fmaxf(acc2, 0.f);

    if (e < 3) att_out[(size_t)b * 3 + e] = att[e];
}

// ---------------------------------------------------------------------------
extern "C" void kernel_launch(void* const* d_in, const int* in_sizes, int n_in,
                              void* d_out, int out_size, void* d_ws, size_t ws_size,
                              hipStream_t stream) {
    const int*   nodes      = (const int*)d_in[0];
    const int*   neigh_idx  = (const int*)d_in[1];
    const float* node_emb   = (const float*)d_in[2];
    const float* node_prof  = (const float*)d_in[3];
    const float* neigh_emb  = (const float*)d_in[4];
    const float* neigh_prof = (const float*)d_in[5];
    const float* W_f = (const float*)d_in[6];  const float* b_f = (const float*)d_in[7];
    const float* Wa1 = (const float*)d_in[8];  const float* ba1 = (const float*)d_in[9];
    const float* Wa2 = (const float*)d_in[10]; const float* ba2 = (const float*)d_in[11];
    const float* Wa3 = (const float*)d_in[12]; const float* ba3 = (const float*)d_in[13];
    const float* W1  = (const float*)d_in[14]; const float* b1  = (const float*)d_in[15];
    const float* W2  = (const float*)d_in[16]; const float* b2  = (const float*)d_in[17];
    const float* Wc  = (const float*)d_in[18]; const float* bc  = (const float*)d_in[19];
    const float* Wt  = (const float*)d_in[20];

    float* out     = (float*)d_out;
    float* att_out = out + (size_t)B_ * E_;

    char* ws = (char*)d_ws;
    __bf16* nodes_fusion = (__bf16*)(ws);                       // 1 MB @ 0
    float*  node_pre     = (float*)(ws + (1u << 20));           // 2 MB @ 1M
    __bf16* type_agg     = (__bf16*)(ws + (3u << 20));          // 3 MB @ 3M
    __bf16* aggB         = (__bf16*)(ws + (6u << 20));          // 3 MB @ 6M
    __bf16* WtF          = (__bf16*)(ws + (9u << 20));          // 64 KB
    __bf16* Wa1t         = (__bf16*)(ws + (9u << 20) + 65536);
    __bf16* Wa2t         = (__bf16*)(ws + (9u << 20) + 98304);
    __bf16* W1t          = (__bf16*)(ws + (9u << 20) + 131072);
    __bf16* NFt          = (__bf16*)(ws + (16u << 20));         // 76.8 MB @ 16M

    k_prep<<<dim3(128, 4), 256, 0, stream>>>(W_f, Wa1, Wa2, W1, WtF, Wa1t, Wa2t, W1t);
    k_node_fusion<<<B_, 128, 0, stream>>>(nodes, node_emb, node_prof, W_f, b_f,
                                          nodes_fusion);
    k_node_pre<<<B_, 128, 0, stream>>>(nodes_fusion, Wa1, ba1, node_pre);
    k_nf<<<NF_GRID, 256, 0, stream>>>(neigh_emb, neigh_prof, WtF, b_f, NFt);
    k_att<<<ATT_GRID, 256, 0, stream>>>(neigh_idx, NFt, Wa1t, Wa2t, ba2,
                                        Wa3, ba3, node_pre, aggB);
    k_w1<<<(B_ * T_) / 64, 256, 0, stream>>>(aggB, W1t, b1, type_agg);
    k_final<<<B_, 128, 0, stream>>>(type_agg, nodes_fusion, Wt, W2, b2, Wc, bc,
                                    out, att_out);
}

// Round 10
// 300.408 us; speedup vs baseline: 1.3992x; 1.3992x over previous
//
#include <hip/hip_runtime.h>
#include <hip/hip_bf16.h>

#define B_ 4096
#define K_ 64
#define N_ 100000
#define E_ 128
#define T_ 3

typedef __bf16 bf16x8 __attribute__((ext_vector_type(8)));
typedef float  f32x4  __attribute__((ext_vector_type(4)));

static __device__ __forceinline__ bf16x8 cvt8r(f32x4 u, f32x4 v) {
    bf16x8 o;
    o[0] = (__bf16)u[0]; o[1] = (__bf16)u[1]; o[2] = (__bf16)u[2]; o[3] = (__bf16)u[3];
    o[4] = (__bf16)v[0]; o[5] = (__bf16)v[1]; o[6] = (__bf16)v[2]; o[7] = (__bf16)v[3];
    return o;
}

typedef const __attribute__((address_space(1))) void GAS;
typedef __attribute__((address_space(3))) void LAS;
static __device__ __forceinline__ void gload16(const void* g, void* l) {
    __builtin_amdgcn_global_load_lds((GAS*)g, (LAS*)l, 16, 0, 0);
}

#define MFMA16(a, b, c) __builtin_amdgcn_mfma_f32_16x16x32_bf16((a), (b), (c), 0, 0, 0)

// ---------------------------------------------------------------------------
// Kernel 0: transpose + bf16-convert weight matrices.
// ---------------------------------------------------------------------------
__global__ __launch_bounds__(256)
void k_prep(const float* __restrict__ W_f, const float* __restrict__ Wa1,
            const float* __restrict__ Wa2, const float* __restrict__ W1,
            __bf16* __restrict__ WtF, __bf16* __restrict__ Wa1t,
            __bf16* __restrict__ Wa2t, __bf16* __restrict__ W1t) {
    const int n = blockIdx.x;
    const int k = threadIdx.x;
    if (blockIdx.y == 0) {
        WtF[n * 256 + k] = (__bf16)W_f[k * 128 + n];
    } else if (blockIdx.y == 1) {
        if (k < 128) Wa1t[n * 128 + k] = (__bf16)Wa1[k * 128 + n];
    } else if (blockIdx.y == 2) {
        if (k < 128) Wa2t[n * 128 + k] = (__bf16)Wa2[k * 128 + n];
    } else {
        if (k < 128) W1t[n * 128 + k] = (__bf16)W1[k * 128 + n];
    }
}

// ---------------------------------------------------------------------------
// Kernel 1: nodes_fusion
// ---------------------------------------------------------------------------
__global__ __launch_bounds__(128)
void k_node_fusion(const int* __restrict__ nodes,
                   const float* __restrict__ node_emb,
                   const float* __restrict__ node_prof,
                   const float* __restrict__ W_f, const float* __restrict__ b_f,
                   __bf16* __restrict__ nodes_fusion) {
    __shared__ float x[256];
    const int b = blockIdx.x;
    const int e = threadIdx.x;
    const int nd = nodes[b];
    x[e]       = node_emb[(size_t)nd * E_ + e];
    x[128 + e] = node_prof[(size_t)nd * E_ + e];
    __syncthreads();
    float acc = b_f[e];
#pragma unroll 8
    for (int i = 0; i < 256; ++i) acc = fmaf(x[i], W_f[i * E_ + e], acc);
    nodes_fusion[(size_t)b * E_ + e] = (__bf16)fmaxf(acc, 0.f);
}

// ---------------------------------------------------------------------------
// Kernel 1b: node_pre (f32)
// ---------------------------------------------------------------------------
__global__ __launch_bounds__(128)
void k_node_pre(const __bf16* __restrict__ nodes_fusion,
                const float* __restrict__ Wa1, const float* __restrict__ ba1,
                float* __restrict__ node_pre) {
    __shared__ float x[128];
    const int b = blockIdx.x;
    const int c = threadIdx.x;
    x[c] = (float)nodes_fusion[(size_t)b * E_ + c];
    __syncthreads();
    float acc = ba1[c];
#pragma unroll 8
    for (int i = 0; i < 128; ++i) acc = fmaf(x[i], Wa1[(128 + i) * E_ + c], acc);
    node_pre[(size_t)b * E_ + c] = acc;
}

// ---------------------------------------------------------------------------
// Kernel NF v4 (unchanged): persistent pipelined precompute.
// ---------------------------------------------------------------------------
#define NF_GRID 1024
#define NF_TPT (N_ / 16)
#define NF_NJOB (NF_TPT * T_)

__global__ __launch_bounds__(256, 4)
void k_nf(const float* __restrict__ neigh_emb,
          const float* __restrict__ neigh_prof,
          const __bf16* __restrict__ WtF, const float* __restrict__ b_f,
          __bf16* __restrict__ NFt) {
    __shared__ __align__(16) float  Xf[2][16 * 256];
    __shared__ __align__(16) __bf16 NFl[16 * 128];

    const int tid  = threadIdx.x;
    const int wid  = tid >> 6, lane = tid & 63;
    const int lr   = lane & 15, lk = lane >> 4;

    bf16x8 wf[16];
#pragma unroll
    for (int ks = 0; ks < 8; ++ks)
#pragma unroll
        for (int n = 0; n < 2; ++n)
            wf[ks * 2 + n] = *(const bf16x8*)&WtF[
                (size_t)(wid * 32 + n * 16 + lr) * 256 + ks * 32 + lk * 8];
    const float bb0 = b_f[wid * 32 + lr];
    const float bb1 = b_f[wid * 32 + 16 + lr];

    auto stage = [&](int j, int buf) {
        const int t    = j / NF_TPT;
        const int base = (j - t * NF_TPT) * 16;
        const float* embT  = neigh_emb  + (size_t)t * N_ * E_;
        const float* profT = neigh_prof + (size_t)t * N_ * E_;
#pragma unroll
        for (int i = 0; i < 4; ++i) {
            const int r  = wid * 4 + i;
            const int id = base + r;
            const int g  = lane ^ (r & 15);
            const float* src = (g < 32)
                ? embT  + (size_t)id * E_ + g * 4
                : profT + (size_t)id * E_ + (g - 32) * 4;
            gload16(src, (char*)&Xf[buf][0] + r * 1024);
        }
    };

    int job = blockIdx.x;
    stage(job, 0);
    int cur = 0;
    bool first = true;

    for (; job < NF_NJOB; job += NF_GRID) {
        const int tc    = job / NF_TPT;
        const int basec = (job - tc * NF_TPT) * 16;

        if (first) { asm volatile("s_waitcnt vmcnt(0)" ::: "memory"); first = false; }
        else       { asm volatile("s_waitcnt vmcnt(1)" ::: "memory"); }
        __builtin_amdgcn_s_barrier();
        __builtin_amdgcn_sched_barrier(0);

        const int nxt = job + NF_GRID;
        if (nxt < NF_NJOB) stage(nxt, cur ^ 1);

        const float* X = &Xf[cur][0];

        {
            f32x4 acc1[2] = {};
#pragma unroll
            for (int ks = 0; ks < 8; ++ks) {
                const int g0 = ks * 8 + lk * 2;
                const f32x4 u0 = *(const f32x4*)&X[lr * 256 + ((g0 ^ lr) << 2)];
                const f32x4 v0 = *(const f32x4*)&X[lr * 256 + (((g0 + 1) ^ lr) << 2)];
                const bf16x8 a0 = cvt8r(u0, v0);
                acc1[0] = MFMA16(a0, wf[ks * 2 + 0], acc1[0]);
                acc1[1] = MFMA16(a0, wf[ks * 2 + 1], acc1[1]);
            }
#pragma unroll
            for (int n = 0; n < 2; ++n) {
                const int c = wid * 32 + n * 16 + lr;
                const float bb = n ? bb1 : bb0;
                const int q = c >> 3, eo = c & 7;
#pragma unroll
                for (int j = 0; j < 4; ++j) {
                    const int rN = lk * 4 + j;
                    NFl[rN * 128 + ((q ^ rN) << 3) + eo] =
                        (__bf16)fmaxf(acc1[n][j] + bb, 0.f);
                }
            }
        }
        asm volatile("s_waitcnt lgkmcnt(0)" ::: "memory");
        __builtin_amdgcn_s_barrier();
        __builtin_amdgcn_sched_barrier(0);

        {
            const int rr = tid >> 4, qq = tid & 15;
            const int p = qq ^ (rr & 15);
            __bf16* outp = NFt + ((size_t)tc * N_ + basec + rr) * E_ + qq * 8;
            *(bf16x8*)outp = *(const bf16x8*)&NFl[rr * 128 + (p << 3)];
        }
        cur ^= 1;
    }
}

// ---------------------------------------------------------------------------
// Kernel ATT v4: same structure as v3 (persistent, double-buffered gather,
// register weights), but __launch_bounds__(256, 2) -> 256-VGPR cap so the
// weight fragments STAY in registers (v3's (256,3) = 170 cap spilled them:
// FETCH 432 MB / WRITE 47 MB of scratch traffic, VGPR_Count 84).
// Grid 512 = 2 blocks/CU exactly; 24 iterations.
// ---------------------------------------------------------------------------
#define ATT_GRID 512
#define ATT_NJOB (B_ * T_)
#define ATT_NITER (ATT_NJOB / ATT_GRID)   /* 24, exact */

__global__ __launch_bounds__(256, 2)
void k_att(const int* __restrict__ neigh_idx,
           const __bf16* __restrict__ NFt,
           const __bf16* __restrict__ Wa1t,
           const __bf16* __restrict__ Wa2t,
           const float* __restrict__ ba2,
           const float* __restrict__ Wa3, const float* __restrict__ ba3,
           const float* __restrict__ node_pre,
           __bf16* __restrict__ aggB) {
    __shared__ __align__(16) __bf16 Nb[2][64 * 128];   // 2 x 16 KB
    __shared__ __align__(16) __bf16 H1l[64 * 128];     // 16 KB
    __shared__ float scp[4 * 64];                      // 1 KB
    __shared__ float red4[4 * 128];                    // 2 KB

    const int tid = threadIdx.x;
    const int wid = tid >> 6, lane = tid & 63;
    const int lr = lane & 15, lk = lane >> 4;

    // ---- preload weights (wave owns cols wid*32..+32 in BOTH GEMMs) ----
    bf16x8 wa1r[8], wa2r[8];
#pragma unroll
    for (int ks = 0; ks < 4; ++ks)
#pragma unroll
        for (int n = 0; n < 2; ++n) {
            wa1r[ks * 2 + n] = *(const bf16x8*)&Wa1t[
                (size_t)(wid * 32 + n * 16 + lr) * 128 + ks * 32 + lk * 8];
            wa2r[ks * 2 + n] = *(const bf16x8*)&Wa2t[
                (size_t)(wid * 32 + n * 16 + lr) * 128 + ks * 32 + lk * 8];
        }
    float ba2r[2], wa3r[2];
#pragma unroll
    for (int n = 0; n < 2; ++n) {
        ba2r[n] = ba2[wid * 32 + n * 16 + lr];
        wa3r[n] = Wa3[wid * 32 + n * 16 + lr];
    }
    const float ba3v = ba3[0];

    // DMA stage: per-lane ids in idv (lane m<16 holds row wid*16+m)
    auto stage = [&](int j, int buf, int idv) {
        const int t = j / B_;
        const __bf16* tab = NFt + (size_t)t * N_ * E_;
#pragma unroll
        for (int i = 0; i < 4; ++i) {
            const int rowblock = wid * 16 + i * 4;
            const int rsub = i * 4 + (lane >> 4);        // == row & 15
            const int q = (lane & 15) ^ rsub;
            const int id = __shfl(idv, rsub);
            gload16(tab + (size_t)id * E_ + q * 8,
                    (char*)&Nb[buf][0] + rowblock * 256);
        }
    };

    int job = blockIdx.x;
    {
        const int idv0 = neigh_idx[(size_t)job * K_ + wid * 16 + (lane & 15)];
        stage(job, 0, idv0);
    }
    float npn0 = node_pre[(size_t)(job % B_) * E_ + wid * 32 + lr];
    float npn1 = node_pre[(size_t)(job % B_) * E_ + wid * 32 + 16 + lr];
    int jn = job + ATT_GRID; if (jn >= ATT_NJOB) jn = ATT_NJOB - 1;
    int idnext = neigh_idx[(size_t)jn * K_ + wid * 16 + (lane & 15)];
    int cur = 0;

    for (int it = 0; it < ATT_NITER; ++it, job += ATT_GRID) {
        asm volatile("s_waitcnt vmcnt(0)" ::: "memory");
        __builtin_amdgcn_s_barrier();
        __builtin_amdgcn_sched_barrier(0);

        const float np0 = npn0, np1 = npn1;   // npre for CURRENT job

        if (it + 1 < ATT_NITER) {
            stage(job + ATT_GRID, cur ^ 1, idnext);
            int j2 = job + 2 * ATT_GRID; if (j2 >= ATT_NJOB) j2 = ATT_NJOB - 1;
            idnext = neigh_idx[(size_t)j2 * K_ + wid * 16 + (lane & 15)];
            const int bn = (job + ATT_GRID) % B_;
            npn0 = node_pre[(size_t)bn * E_ + wid * 32 + lr];
            npn1 = node_pre[(size_t)bn * E_ + wid * 32 + 16 + lr];
        }

        const __bf16* NbC = &Nb[cur][0];

        // ---- GEMM2: H1 = relu(NF @ Wa1t + npre), K=128 ----
        {
            f32x4 acc2[4][2] = {};
#pragma unroll
            for (int ks = 0; ks < 4; ++ks) {
                const int q = ks * 4 + lk;
                bf16x8 a[4];
#pragma unroll
                for (int mi = 0; mi < 4; ++mi)
                    a[mi] = *(const bf16x8*)&NbC[(mi * 16 + lr) * 128 + ((q ^ lr) << 3)];
#pragma unroll
                for (int n = 0; n < 2; ++n)
#pragma unroll
                    for (int mi = 0; mi < 4; ++mi)
                        acc2[mi][n] = MFMA16(a[mi], wa1r[ks * 2 + n], acc2[mi][n]);
            }
#pragma unroll
            for (int n = 0; n < 2; ++n) {
                const int col = wid * 32 + n * 16 + lr;
                const float pp = n ? np1 : np0;
                const int q = col >> 3, eo = col & 7;
#pragma unroll
                for (int mi = 0; mi < 4; ++mi)
#pragma unroll
                    for (int j = 0; j < 4; ++j) {
                        const int row = mi * 16 + lk * 4 + j;
                        H1l[row * 128 + ((q ^ (row & 15)) << 3) + eo] =
                            (__bf16)fmaxf(acc2[mi][n][j] + pp, 0.f);
                    }
            }
        }
        asm volatile("s_waitcnt lgkmcnt(0)" ::: "memory");
        __builtin_amdgcn_s_barrier();
        __builtin_amdgcn_sched_barrier(0);

        // ---- GEMM3: H2 = relu(H1 @ Wa2 + ba2) -> score partials ----
        {
            f32x4 acc3[4][2] = {};
#pragma unroll
            for (int ks = 0; ks < 4; ++ks) {
                const int q = ks * 4 + lk;
                bf16x8 a[4];
#pragma unroll
                for (int mi = 0; mi < 4; ++mi)
                    a[mi] = *(const bf16x8*)&H1l[(mi * 16 + lr) * 128 + ((q ^ lr) << 3)];
#pragma unroll
                for (int n = 0; n < 2; ++n)
#pragma unroll
                    for (int mi = 0; mi < 4; ++mi)
                        acc3[mi][n] = MFMA16(a[mi], wa2r[ks * 2 + n], acc3[mi][n]);
            }
#pragma unroll
            for (int mi = 0; mi < 4; ++mi)
#pragma unroll
                for (int j = 0; j < 4; ++j) {
                    float v = fmaxf(acc3[mi][0][j] + ba2r[0], 0.f) * wa3r[0]
                            + fmaxf(acc3[mi][1][j] + ba2r[1], 0.f) * wa3r[1];
                    v += __shfl_xor(v, 1);
                    v += __shfl_xor(v, 2);
                    v += __shfl_xor(v, 4);
                    v += __shfl_xor(v, 8);
                    if (lr == 0)
                        scp[wid * 64 + mi * 16 + lk * 4 + j] = v;
                }
        }
        asm volatile("s_waitcnt lgkmcnt(0)" ::: "memory");
        __builtin_amdgcn_s_barrier();
        __builtin_amdgcn_sched_barrier(0);

        // ---- softmax over K=64, redundantly in every wave (att in regs) ----
        float att;
        {
            const float v = scp[lane] + scp[64 + lane] + scp[128 + lane]
                          + scp[192 + lane] + ba3v;
            float m = v;
#pragma unroll
            for (int o = 32; o > 0; o >>= 1) m = fmaxf(m, __shfl_xor(m, o));
            const float pe = __expf(v - m);
            float s = pe;
#pragma unroll
            for (int o = 32; o > 0; o >>= 1) s += __shfl_xor(s, o);
            att = pe / s;                       // lane holds att[neighbor=lane]
        }

        // ---- agg partials: wave wid covers rows wid*16..+15, lane -> e,e+64 ----
        {
            float p0 = 0.f, p1 = 0.f;
            const int q0 = lane >> 3, eo = lane & 7;
            const int q1 = (lane + 64) >> 3;
#pragma unroll
            for (int i = 0; i < 16; ++i) {
                const int row = wid * 16 + i;
                const float av = __shfl(att, row);
                p0 = fmaf(av, (float)NbC[row * 128 + ((q0 ^ (row & 15)) << 3) + eo], p0);
                p1 = fmaf(av, (float)NbC[row * 128 + ((q1 ^ (row & 15)) << 3) + eo], p1);
            }
            red4[wid * 128 + lane] = p0;
            red4[wid * 128 + 64 + lane] = p1;
        }
        asm volatile("s_waitcnt lgkmcnt(0)" ::: "memory");
        __builtin_amdgcn_s_barrier();
        __builtin_amdgcn_sched_barrier(0);

        if (tid < 128) {
            const float s = red4[tid] + red4[128 + tid] + red4[256 + tid]
                          + red4[384 + tid];
            const int bcur = job % B_, tcur = job / B_;
            aggB[((size_t)bcur * T_ + tcur) * E_ + tid] = (__bf16)s;
        }
        cur ^= 1;
    }
}

// ---------------------------------------------------------------------------
// Kernel 2b: type_agg = relu(aggB @ W1 + b1), M=B*T=12288, K=N=128.
// ---------------------------------------------------------------------------
__global__ __launch_bounds__(256)
void k_w1(const __bf16* __restrict__ aggB, const __bf16* __restrict__ W1t,
          const float* __restrict__ b1, __bf16* __restrict__ type_agg) {
    const int tid  = threadIdx.x;
    const int wid  = tid >> 6;
    const int lane = tid & 63;
    const int lr   = lane & 15;
    const int lk   = lane >> 4;
    const int rbase = blockIdx.x * 64 + wid * 16;

    f32x4 acc[8] = {};
#pragma unroll
    for (int ks = 0; ks < 4; ++ks) {
        const bf16x8 a = *(const bf16x8*)&aggB[(size_t)(rbase + lr) * 128 + ks * 32 + lk * 8];
        const __bf16* wb = W1t + (size_t)lr * 128 + ks * 32 + lk * 8;
#pragma unroll
        for (int n = 0; n < 8; ++n) {
            const bf16x8 w = *(const bf16x8*)(wb + (size_t)n * 16 * 128);
            acc[n] = MFMA16(a, w, acc[n]);
        }
    }
#pragma unroll
    for (int n = 0; n < 8; ++n) {
        const int col = n * 16 + lr;
        const float bb = b1[col];
#pragma unroll
        for (int j = 0; j < 4; ++j) {
            const int row = rbase + lk * 4 + j;
            type_agg[(size_t)row * 128 + col] = (__bf16)fmaxf(acc[n][j] + bb, 0.f);
        }
    }
}

// ---------------------------------------------------------------------------
// Kernel 3: type softmax + final MLP + output head.
// ---------------------------------------------------------------------------
__global__ __launch_bounds__(128)
void k_final(const __bf16* __restrict__ type_agg,
             const __bf16* __restrict__ nodes_fusion,
             const float* __restrict__ Wt,
             const float* __restrict__ W2, const float* __restrict__ b2,
             const float* __restrict__ Wc, const float* __restrict__ bc,
             float* __restrict__ out, float* __restrict__ att_out) {
    __shared__ float ta[384];
    __shared__ float nfu[128];
    __shared__ float fin[128];
    __shared__ float hb[128];
    __shared__ float att[3];
    __shared__ float red[3][128];

    const int b = blockIdx.x;
    const int e = threadIdx.x;

    const float v0 = (float)type_agg[(size_t)b * 384 + e];
    const float v1 = (float)type_agg[(size_t)b * 384 + 128 + e];
    const float v2 = (float)type_agg[(size_t)b * 384 + 256 + e];
    ta[e] = v0; ta[128 + e] = v1; ta[256 + e] = v2;
    nfu[e] = (float)nodes_fusion[(size_t)b * E_ + e];

    float p0, p1, p2;
    {
        const float* w0 = Wt + (size_t)e * 3;
        const float* w1 = Wt + (size_t)(128 + e) * 3;
        const float* w2 = Wt + (size_t)(256 + e) * 3;
        p0 = v0 * w0[0] + v1 * w1[0] + v2 * w2[0];
        p1 = v0 * w0[1] + v1 * w1[1] + v2 * w2[1];
        p2 = v0 * w0[2] + v1 * w1[2] + v2 * w2[2];
    }
    red[0][e] = p0; red[1][e] = p1; red[2][e] = p2;
    __syncthreads();

    if (e < 3) {
        float s = 0.f;
        for (int i = 0; i < 128; ++i) s += red[e][i];
        red[e][0] = s;
    }
    __syncthreads();
    if (e == 0) {
        const float s0 = red[0][0], s1 = red[1][0], s2 = red[2][0];
        const float m  = fmaxf(s0, fmaxf(s1, s2));
        const float e0 = __expf(s0 - m), e1 = __expf(s1 - m), e2 = __expf(s2 - m);
        const float inv = 1.f / (e0 + e1 + e2);
        att[0] = e0 * inv; att[1] = e1 * inv; att[2] = e2 * inv;
    }
    __syncthreads();

    fin[e] = att[0] * ta[e] + att[1] * ta[128 + e] + att[2] * ta[256 + e];
    __syncthreads();

    float acc = b2[e];
#pragma unroll 8
    for (int i = 0; i < 128; ++i) acc = fmaf(fin[i], W2[i * E_ + e], acc);
    hb[e] = fmaxf(acc, 0.f);
    __syncthreads();

    float acc2 = bc[e];
#pragma unroll 8
    for (int i = 0; i < 128; ++i) acc2 = fmaf(nfu[i], Wc[i * E_ + e], acc2);
#pragma unroll 8
    for (int i = 0; i < 128; ++i) acc2 = fmaf(hb[i], Wc[(128 + i) * E_ + e], acc2);
    out[(size_t)b * E_ + e] = fmaxf(acc2, 0.f);

    if (e < 3) att_out[(size_t)b * 3 + e] = att[e];
}

// ---------------------------------------------------------------------------
extern "C" void kernel_launch(void* const* d_in, const int* in_sizes, int n_in,
                              void* d_out, int out_size, void* d_ws, size_t ws_size,
                              hipStream_t stream) {
    const int*   nodes      = (const int*)d_in[0];
    const int*   neigh_idx  = (const int*)d_in[1];
    const float* node_emb   = (const float*)d_in[2];
    const float* node_prof  = (const float*)d_in[3];
    const float* neigh_emb  = (const float*)d_in[4];
    const float* neigh_prof = (const float*)d_in[5];
    const float* W_f = (const float*)d_in[6];  const float* b_f = (const float*)d_in[7];
    const float* Wa1 = (const float*)d_in[8];  const float* ba1 = (const float*)d_in[9];
    const float* Wa2 = (const float*)d_in[10]; const float* ba2 = (const float*)d_in[11];
    const float* Wa3 = (const float*)d_in[12]; const float* ba3 = (const float*)d_in[13];
    const float* W1  = (const float*)d_in[14]; const float* b1  = (const float*)d_in[15];
    const float* W2  = (const float*)d_in[16]; const float* b2  = (const float*)d_in[17];
    const float* Wc  = (const float*)d_in[18]; const float* bc  = (const float*)d_in[19];
    const float* Wt  = (const float*)d_in[20];

    float* out     = (float*)d_out;
    float* att_out = out + (size_t)B_ * E_;

    char* ws = (char*)d_ws;
    __bf16* nodes_fusion = (__bf16*)(ws);                       // 1 MB @ 0
    float*  node_pre     = (float*)(ws + (1u << 20));           // 2 MB @ 1M
    __bf16* type_agg     = (__bf16*)(ws + (3u << 20));          // 3 MB @ 3M
    __bf16* aggB         = (__bf16*)(ws + (6u << 20));          // 3 MB @ 6M
    __bf16* WtF          = (__bf16*)(ws + (9u << 20));          // 64 KB
    __bf16* Wa1t         = (__bf16*)(ws + (9u << 20) + 65536);
    __bf16* Wa2t         = (__bf16*)(ws + (9u << 20) + 98304);
    __bf16* W1t          = (__bf16*)(ws + (9u << 20) + 131072);
    __bf16* NFt          = (__bf16*)(ws + (16u << 20));         // 76.8 MB @ 16M

    k_prep<<<dim3(128, 4), 256, 0, stream>>>(W_f, Wa1, Wa2, W1, WtF, Wa1t, Wa2t, W1t);
    k_node_fusion<<<B_, 128, 0, stream>>>(nodes, node_emb, node_prof, W_f, b_f,
                                          nodes_fusion);
    k_node_pre<<<B_, 128, 0, stream>>>(nodes_fusion, Wa1, ba1, node_pre);
    k_nf<<<NF_GRID, 256, 0, stream>>>(neigh_emb, neigh_prof, WtF, b_f, NFt);
    k_att<<<ATT_GRID, 256, 0, stream>>>(neigh_idx, NFt, Wa1t, Wa2t, ba2,
                                        Wa3, ba3, node_pre, aggB);
    k_w1<<<(B_ * T_) / 64, 256, 0, stream>>>(aggB, W1t, b1, type_agg);
    k_final<<<B_, 128, 0, stream>>>(type_agg, nodes_fusion, Wt, W2, b2, Wc, bc,
                                    out, att_out);
}